// Round 10
// baseline (383.055 us; speedup 1.0000x reference)
//
#include <hip/hip_runtime.h>
#include <hip/hip_bf16.h>

// RGCN basis-decomposition forward, round 10.
//
// Two changes vs round 9 (separate kernels -> clean attribution):
//  1. k_fused proj-role epilogue: two 16-row passes through a HALF-size Clds
//     (33KB -> 16.6KB; total LDS 37.9 -> ~21.2KB). Round-9 evidence:
//     occupancy 19% with all pipes idle -> latency-bound on too few waves;
//     LDS was the resident-block limiter.
//  2. k_agg_emb: 16 chains/wave (was 8). Round-7 showed latency-chain
//     batching is the lever; double the MLP depth. Grid 1563 with tail guard.

constexpr int NNODES = 100000;
constexpr int NEDGES = 1600000;

// ---- workspace layouts (bytes) ----
constexpr size_t WF_BYTES  = (size_t)NNODES * 512 * 2;         // 102,400,000
constexpr size_t HEADE_OFF = WF_BYTES;                         // int[N]
constexpr size_t REC_OFF   = HEADE_OFF + (size_t)NNODES * 4;   // int4[E]
constexpr size_t WS_NEED_E = REC_OFF + (size_t)NEDGES * 16;    // 128,400,000
constexpr size_t WCAT_OFF  = WS_NEED_E;                        // bf16[576][64]
constexpr size_t WS_NEED_M = WCAT_OFF + (size_t)576 * 64 * 2;  // 128,473,728
// round-5 split path:
constexpr size_t HEAD_OFF  = WF_BYTES;
constexpr size_t NEXT_OFF  = HEAD_OFF + (size_t)NNODES * 4;
constexpr size_t WS_NEED   = NEXT_OFF + (size_t)NEDGES * 4;    // 109,200,000

typedef __attribute__((ext_vector_type(8))) short short8v;  // 8 bf16 (4 VGPR)
typedef __attribute__((ext_vector_type(4))) float f32x4;    // MFMA acc

// ---------------------------------------------------------------------------
// k_wcat: Wcat_t[c][i] (c = output col 0..575, i = input feat 0..63), bf16.
// ---------------------------------------------------------------------------
__global__ __launch_bounds__(256)
void k_wcat(const float* __restrict__ weight, const float* __restrict__ w_comp,
            const float* __restrict__ loop_w, __hip_bfloat16* __restrict__ wcat)
{
    const int idx = blockIdx.x * 256 + threadIdx.x;   // grid 144 -> 36864
    if (idx >= 576 * 64) return;
    const int c = idx >> 6, i = idx & 63;
    float v;
    if (c < 512) {
        const int r = c >> 6, o = c & 63;
        v = w_comp[r * 4 + 0] * weight[        i * 64 + o]
          + w_comp[r * 4 + 1] * weight[ 4096 + i * 64 + o]
          + w_comp[r * 4 + 2] * weight[ 8192 + i * 64 + o]
          + w_comp[r * 4 + 3] * weight[12288 + i * 64 + o];
    } else {
        v = loop_w[i * 64 + (c - 512)];
    }
    wcat[(size_t)c * 64 + i] = __float2bfloat16(v);
}

// ---------------------------------------------------------------------------
// k_fused: interleaved proj-MFMA + link-emb roles. Grid 4687:
//   bid%3<2 -> proj tile (g*2+r in 0..3124); bid%3==2 -> link grid-stride.
// proj epilogue now runs in TWO 16-row passes through Clds16 (half LDS).
// ---------------------------------------------------------------------------
__global__ __launch_bounds__(256)
void k_fused(const float* __restrict__ feat,
             const __hip_bfloat16* __restrict__ wcat,   // [576][64]
             const float* __restrict__ h_bias,
             __hip_bfloat16* __restrict__ wfeat,        // [N][512]
             float* __restrict__ out,                   // [N][64]
             const int* __restrict__ src, const int* __restrict__ dst,
             const int* __restrict__ et, const float* __restrict__ norm,
             int* __restrict__ head, int4* __restrict__ rec)
{
    __shared__ __hip_bfloat16 Alds[32 * 72];     // A tile, +8 pad   (4.6KB)
    __shared__ __hip_bfloat16 Clds16[16 * 520];  // 16-row C buffer (16.6KB)

    const int bid = blockIdx.x;
    const int t = threadIdx.x;
    const int g = bid / 3;
    const int rrole = bid - g * 3;

    if (rrole == 2) {
        // ================= link role (1562 blocks) =================
        const int i = g * 256 + t;
        const int stride = 1562 * 256;
        for (int e = i; e < NEDGES; e += stride) {
            const int d = dst[e];
            const int s = src[e];
            const int rr = et[e];
            const float nm = norm[e];
            const int old = atomicExch(&head[d], e);
            rec[e] = make_int4(old, s * 512 + rr * 64, __float_as_int(nm), 0);
        }
        return;
    }

    // ================= proj role (3125 blocks) =================
    const int pidx = g * 2 + rrole;          // 0..3124
    const int lane = t & 63;
    const int wv = t >> 6;                   // 0..3
    const int nbase = pidx * 32;

    // ---- stage feat tile (32x64 f32 -> bf16 LDS), coalesced float4 ----
    {
        const float4* fsrc = (const float4*)(feat + (size_t)nbase * 64);
        #pragma unroll
        for (int kk = 0; kk < 2; ++kk) {
            const int idx = t + kk * 256;          // 0..511 float4s
            const float4 f = fsrc[idx];
            const int row = idx >> 4;
            const int c4  = (idx & 15) * 4;
            __hip_bfloat16* p = &Alds[row * 72 + c4];
            p[0] = __float2bfloat16(f.x);
            p[1] = __float2bfloat16(f.y);
            p[2] = __float2bfloat16(f.z);
            p[3] = __float2bfloat16(f.w);
        }
    }
    __syncthreads();

    const int colbase = wv * 144;
    const int lr = lane & 15;
    const int lg = lane >> 4;

    f32x4 acc[2][9];
    #pragma unroll
    for (int mf = 0; mf < 2; ++mf)
        #pragma unroll
        for (int nf = 0; nf < 9; ++nf)
            acc[mf][nf] = (f32x4){0.f, 0.f, 0.f, 0.f};

    #pragma unroll
    for (int ks = 0; ks < 2; ++ks) {
        short8v a[2];
        #pragma unroll
        for (int mf = 0; mf < 2; ++mf)
            a[mf] = *(const short8v*)&Alds[(mf * 16 + lr) * 72 + ks * 32 + lg * 8];
        short8v b[9];
        #pragma unroll
        for (int nf = 0; nf < 9; ++nf) {
            const int col = colbase + nf * 16 + lr;
            b[nf] = *(const short8v*)&wcat[(size_t)col * 64 + ks * 32 + lg * 8];
        }
        #pragma unroll
        for (int mf = 0; mf < 2; ++mf)
            #pragma unroll
            for (int nf = 0; nf < 9; ++nf)
                acc[mf][nf] = __builtin_amdgcn_mfma_f32_16x16x32_bf16(
                    a[mf], b[nf], acc[mf][nf], 0, 0, 0);
    }

    // ---- epilogue: two 16-row passes (mf = 0: rows 0-15, mf = 1: 16-31) ----
    #pragma unroll
    for (int mf = 0; mf < 2; ++mf) {
        if (mf) __syncthreads();   // protect Clds16 reuse across passes
        #pragma unroll
        for (int nf = 0; nf < 9; ++nf) {
            const int gc = colbase + nf * 16 + lr;   // frag col (uniform <512)
            const int mrow = lg * 4;                 // 0..12 within pass
            if (gc < 512) {
                #pragma unroll
                for (int q = 0; q < 4; ++q)
                    Clds16[(mrow + q) * 520 + gc] = __float2bfloat16(acc[mf][nf][q]);
            } else {
                const int o = gc - 512;
                const float bias = h_bias[o];
                #pragma unroll
                for (int q = 0; q < 4; ++q)
                    out[(size_t)(nbase + mf * 16 + mrow + q) * 64 + o]
                        = bias + acc[mf][nf][q];
            }
        }
        __syncthreads();
        // coalesced wfeat store: 16 rows, 4 waves x 4 rows (1KB each)
        #pragma unroll
        for (int p = 0; p < 4; ++p) {
            const int node = p * 4 + wv;            // 0..15
            const uint4 v = *(const uint4*)&Clds16[node * 520 + lane * 8];
            *(uint4*)((char*)(wfeat + (size_t)(nbase + mf * 16 + node) * 512)
                      + lane * 16) = v;
        }
    }
}

// ---------------------------------------------------------------------------
// K_agg_emb: 16 concurrent register chain-walks per wave (was 8).
// Batch-then-consume phases preserved; tail-guarded for N % 16 grid.
// ---------------------------------------------------------------------------
__global__ __launch_bounds__(256)
void k_agg_emb(const int* __restrict__ head, const int4* __restrict__ rec,
               const __hip_bfloat16* __restrict__ wfeat,
               float* __restrict__ out)
{
    const int lane = threadIdx.x & 63;
    const int wid = (int)((blockIdx.x * blockDim.x + threadIdx.x) >> 6);
    const int n0 = wid * 16;

    int   e[16];
    float acc[16];
    bool alive = false;
    #pragma unroll
    for (int k = 0; k < 16; ++k) {
        const int n = n0 + k;
        e[k] = (n < NNODES) ? head[n] : -1;
        acc[k] = 0.0f;
        alive = alive || (e[k] >= 0);
    }

    while (alive) {
        // phase 1: batched, unconditional rec loads
        int4 R[16];
        #pragma unroll
        for (int k = 0; k < 16; ++k) {
            const int idx = (e[k] >= 0) ? e[k] : 0;
            R[k] = rec[idx];
        }
        // phase 2: batched gathers
        float w[16];
        #pragma unroll
        for (int k = 0; k < 16; ++k)
            w[k] = __bfloat162float(wfeat[(size_t)R[k].y + lane]);
        // phase 3: accumulate + advance
        alive = false;
        #pragma unroll
        for (int k = 0; k < 16; ++k) {
            if (e[k] >= 0) {
                acc[k] = fmaf(__int_as_float(R[k].z), w[k], acc[k]);
                e[k] = R[k].x;
            }
            alive = alive || (e[k] >= 0);
        }
    }

    #pragma unroll
    for (int k = 0; k < 16; ++k) {
        const int n = n0 + k;
        if (n < NNODES)
            out[(size_t)n * 64 + lane] += acc[k];
    }
}

// ---------------------------------------------------------------------------
// Fallback kernels (proven in earlier rounds).
// ---------------------------------------------------------------------------
__global__ __launch_bounds__(256)
void k_link_emb(const int* __restrict__ src, const int* __restrict__ dst,
                const int* __restrict__ et, const float* __restrict__ norm,
                int* __restrict__ head, int4* __restrict__ rec)
{
    const int i = blockIdx.x * blockDim.x + threadIdx.x;
    const int stride = gridDim.x * blockDim.x;
    for (int e = i; e < NEDGES; e += stride) {
        const int d = dst[e];
        const int s = src[e];
        const int r = et[e];
        const float nm = norm[e];
        const int old = atomicExch(&head[d], e);
        rec[e] = make_int4(old, s * 512 + r * 64, __float_as_int(nm), 0);
    }
}

__global__ __launch_bounds__(256)
void k_agg_emb8(const int* __restrict__ head, const int4* __restrict__ rec,
                const __hip_bfloat16* __restrict__ wfeat,
                float* __restrict__ out)
{
    const int lane = threadIdx.x & 63;
    const int wid = (int)((blockIdx.x * blockDim.x + threadIdx.x) >> 6);
    const int n0 = wid * 8;

    int   e[8];
    float acc[8];
    bool alive = false;
    #pragma unroll
    for (int k = 0; k < 8; ++k) {
        e[k] = head[n0 + k];
        acc[k] = 0.0f;
        alive = alive || (e[k] >= 0);
    }

    while (alive) {
        int4 R[8];
        #pragma unroll
        for (int k = 0; k < 8; ++k) {
            const int idx = (e[k] >= 0) ? e[k] : 0;
            R[k] = rec[idx];
        }
        float w[8];
        #pragma unroll
        for (int k = 0; k < 8; ++k)
            w[k] = __bfloat162float(wfeat[(size_t)R[k].y + lane]);
        alive = false;
        #pragma unroll
        for (int k = 0; k < 8; ++k) {
            if (e[k] >= 0) {
                acc[k] = fmaf(__int_as_float(R[k].z), w[k], acc[k]);
                e[k] = R[k].x;
            }
            alive = alive || (e[k] >= 0);
        }
    }

    #pragma unroll
    for (int k = 0; k < 8; ++k)
        out[(size_t)(n0 + k) * 64 + lane] += acc[k];
}

template <int PATH>
__global__ __launch_bounds__(256)
void rgcn_proj(const float* __restrict__ feat,
               const float* __restrict__ weight,
               const float* __restrict__ w_comp,
               const float* __restrict__ h_bias,
               const float* __restrict__ loop_w,
               __hip_bfloat16* __restrict__ table,
               float* __restrict__ out)
{
    __shared__ float featl[32 * 64];

    const int t = threadIdx.x;
    const int nbase = blockIdx.x * 32;

    {
        const float4* fsrc = (const float4*)(feat + (size_t)nbase * 64);
        float4* fdst = (float4*)featl;
        fdst[t] = fsrc[t];
        fdst[t + 256] = fsrc[t + 256];
    }

    const int lane = t & 63;
    const int n0 = (t >> 6) * 8;
    const float bias = h_bias[lane];

    __syncthreads();

    constexpr int NM = (PATH == 2) ? 1 : 5;
    float acc[8][NM];
    #pragma unroll
    for (int n = 0; n < 8; ++n)
        #pragma unroll
        for (int m = 0; m < NM; ++m)
            acc[n][m] = 0.0f;

    #pragma unroll 4
    for (int i0 = 0; i0 < 64; i0 += 4) {
        float4 f4[8];
        #pragma unroll
        for (int n = 0; n < 8; ++n)
            f4[n] = *(const float4*)&featl[(n0 + n) * 64 + i0];
        #pragma unroll
        for (int q = 0; q < 4; ++q) {
            const int i = i0 + q;
            float vv[NM];
            if (PATH < 2) {
                #pragma unroll
                for (int b = 0; b < 4; ++b)
                    vv[b] = weight[b * 4096 + i * 64 + lane];
                vv[4] = loop_w[i * 64 + lane];
            } else {
                vv[0] = loop_w[i * 64 + lane];
            }
            #pragma unroll
            for (int n = 0; n < 8; ++n) {
                const float fv = (q == 0) ? f4[n].x : (q == 1) ? f4[n].y
                               : (q == 2) ? f4[n].z : f4[n].w;
                #pragma unroll
                for (int m = 0; m < NM; ++m)
                    acc[n][m] = fmaf(fv, vv[m], acc[n][m]);
            }
        }
    }

    float wc[8][4];
    if (PATH == 0) {
        #pragma unroll
        for (int r = 0; r < 8; ++r)
            #pragma unroll
            for (int b = 0; b < 4; ++b)
                wc[r][b] = w_comp[r * 4 + b];
    }

    #pragma unroll
    for (int n = 0; n < 8; ++n) {
        const size_t gn = (size_t)(nbase + n0 + n);
        out[gn * 64 + lane] = bias + acc[n][NM - 1];
        if (PATH == 0) {
            #pragma unroll
            for (int r = 0; r < 8; ++r) {
                const float w = fmaf(wc[r][0], acc[n][0],
                                fmaf(wc[r][1], acc[n][1],
                                fmaf(wc[r][2], acc[n][2],
                                     wc[r][3] * acc[n][3])));
                table[gn * 512 + (size_t)r * 64 + lane] = __float2bfloat16(w);
            }
        } else if (PATH == 1) {
            #pragma unroll
            for (int b = 0; b < 4; ++b)
                table[gn * 256 + (size_t)b * 64 + lane] = __float2bfloat16(acc[n][b]);
        }
    }
}

__global__ __launch_bounds__(256)
void k_link(const int* __restrict__ dst, int* __restrict__ head,
            int* __restrict__ next)
{
    const int i = blockIdx.x * blockDim.x + threadIdx.x;
    const int stride = gridDim.x * blockDim.x;
    for (int e = i; e < NEDGES; e += stride) {
        const int d = dst[e];
        const int old = atomicExch(&head[d], e);
        next[e] = old;
    }
}

__global__ __launch_bounds__(256)
void k_agg(const int* __restrict__ head, const int* __restrict__ next,
           const int* __restrict__ src, const int* __restrict__ et,
           const float* __restrict__ norm,
           const __hip_bfloat16* __restrict__ wfeat,
           float* __restrict__ out)
{
    const int lane = threadIdx.x & 63;
    const int wid = (int)((blockIdx.x * blockDim.x + threadIdx.x) >> 6);
    const int n0 = wid * 8;

    int   e[8];
    float acc[8];
    #pragma unroll
    for (int k = 0; k < 8; ++k) {
        e[k] = head[n0 + k];
        acc[k] = 0.0f;
    }

    while (true) {
        bool progress = false;
        #pragma unroll
        for (int k = 0; k < 8; ++k) {
            const int ek = e[k];
            if (ek >= 0) {
                progress = true;
                const int   s = src[ek];
                const int   r = et[ek];
                const float m = norm[ek];
                const float w = __bfloat162float(
                    wfeat[(size_t)s * 512 + (size_t)r * 64 + lane]);
                acc[k] = fmaf(m, w, acc[k]);
                e[k] = next[ek];
            }
        }
        if (!progress) break;
    }

    #pragma unroll
    for (int k = 0; k < 8; ++k)
        out[(size_t)(n0 + k) * 64 + lane] += acc[k];
}

__global__ __launch_bounds__(256)
void rgcn_edge_a(const int* __restrict__ src, const int* __restrict__ dst,
                 const int* __restrict__ et, const float* __restrict__ norm,
                 const __hip_bfloat16* __restrict__ wfeat,
                 float* __restrict__ out)
{
    const int lane = threadIdx.x & 63;
    const int wid  = (int)((blockIdx.x * blockDim.x + threadIdx.x) >> 6);
    const int nw   = (int)((gridDim.x * blockDim.x) >> 6);
    for (int e = wid; e < NEDGES; e += nw) {
        const int   s  = src[e];
        const int   d  = dst[e];
        const int   r  = et[e];
        const float nm = norm[e];
        const float w  = __bfloat162float(wfeat[(size_t)s * 512 + (size_t)r * 64 + lane]);
        atomicAdd(out + (size_t)d * 64 + lane, w * nm);
    }
}

__global__ __launch_bounds__(256)
void rgcn_edge_b(const int* __restrict__ src, const int* __restrict__ dst,
                 const int* __restrict__ et, const float* __restrict__ norm,
                 const __hip_bfloat16* __restrict__ proj,
                 const float* __restrict__ w_comp,
                 float* __restrict__ out)
{
    const int lane = threadIdx.x & 63;
    const int wid  = (int)((blockIdx.x * blockDim.x + threadIdx.x) >> 6);
    const int nw   = (int)((gridDim.x * blockDim.x) >> 6);
    for (int e = wid; e < NEDGES; e += nw) {
        const int   s  = src[e];
        const int   d  = dst[e];
        const int   r  = et[e];
        const float nm = norm[e];
        const __hip_bfloat16* p = proj + (size_t)s * 256;
        float m = w_comp[r * 4 + 0] * __bfloat162float(p[lane]);
        m = fmaf(w_comp[r * 4 + 1], __bfloat162float(p[ 64 + lane]), m);
        m = fmaf(w_comp[r * 4 + 2], __bfloat162float(p[128 + lane]), m);
        m = fmaf(w_comp[r * 4 + 3], __bfloat162float(p[192 + lane]), m);
        atomicAdd(out + (size_t)d * 64 + lane, m * nm);
    }
}

__global__ __launch_bounds__(256)
void rgcn_edge_c(const int* __restrict__ src, const int* __restrict__ dst,
                 const int* __restrict__ et, const float* __restrict__ norm,
                 const float* __restrict__ feat,
                 const float* __restrict__ weight,
                 const float* __restrict__ w_comp,
                 float* __restrict__ out)
{
    __shared__ __hip_bfloat16 Vl[4 * 64 * 64];
    const int t = threadIdx.x;
    #pragma unroll
    for (int k = 0; k < 64; ++k)
        Vl[t + k * 256] = __float2bfloat16(weight[t + k * 256]);
    __syncthreads();

    const int lane = t & 63;
    const int wid  = (int)((blockIdx.x * blockDim.x + t) >> 6);
    const int nw   = (int)((gridDim.x * blockDim.x) >> 6);
    for (int e = wid; e < NEDGES; e += nw) {
        const int   s  = src[e];
        const int   d  = dst[e];
        const int   r  = et[e];
        const float nm = norm[e];
        const float wc0 = w_comp[r * 4 + 0], wc1 = w_comp[r * 4 + 1];
        const float wc2 = w_comp[r * 4 + 2], wc3 = w_comp[r * 4 + 3];
        const float f = feat[(size_t)s * 64 + lane];
        float acc = 0.0f;
        #pragma unroll 8
        for (int i = 0; i < 64; ++i) {
            const float fi = __shfl(f, i);
            float w =        wc0 * __bfloat162float(Vl[          i * 64 + lane]);
            w = fmaf(wc1, __bfloat162float(Vl[ 4096 + i * 64 + lane]), w);
            w = fmaf(wc2, __bfloat162float(Vl[ 8192 + i * 64 + lane]), w);
            w = fmaf(wc3, __bfloat162float(Vl[12288 + i * 64 + lane]), w);
            acc = fmaf(fi, w, acc);
        }
        atomicAdd(out + (size_t)d * 64 + lane, acc * nm);
    }
}

// ---------------------------------------------------------------------------
extern "C" void kernel_launch(void* const* d_in, const int* in_sizes, int n_in,
                              void* d_out, int out_size, void* d_ws, size_t ws_size,
                              hipStream_t stream) {
    const float* feat   = (const float*)d_in[0];
    const int*   src    = (const int*)  d_in[1];
    const int*   dst    = (const int*)  d_in[2];
    const int*   et     = (const int*)  d_in[3];
    const float* norm   = (const float*)d_in[4];
    const float* weight = (const float*)d_in[5];
    const float* w_comp = (const float*)d_in[6];
    const float* h_bias = (const float*)d_in[7];
    const float* loop_w = (const float*)d_in[8];
    float* out = (float*)d_out;
    char* ws = (char*)d_ws;

    const dim3 gridP(NNODES / 32);  // 3125

    if (ws_size >= WS_NEED_M) {
        // ---- fused MFMA-proj + link path ----
        __hip_bfloat16* wfeat = (__hip_bfloat16*)ws;
        int*  head = (int*)(ws + HEADE_OFF);
        int4* rec  = (int4*)(ws + REC_OFF);
        __hip_bfloat16* wcat = (__hip_bfloat16*)(ws + WCAT_OFF);

        hipMemsetAsync(head, 0xFF, (size_t)NNODES * 4, stream);
        hipLaunchKernelGGL(k_wcat, dim3(144), dim3(256), 0, stream,
                           weight, w_comp, loop_w, wcat);
        hipLaunchKernelGGL(k_fused, dim3(4687), dim3(256), 0, stream,
                           feat, wcat, h_bias, wfeat, out,
                           src, dst, et, norm, head, rec);
        // 16 nodes/wave, 4 waves/block -> 64 nodes/block; ceil(100000/64)=1563
        hipLaunchKernelGGL(k_agg_emb, dim3(1563), dim3(256), 0, stream,
                           head, rec, wfeat, out);
    } else if (ws_size >= WS_NEED_E) {
        // ---- round-7 proven path ----
        __hip_bfloat16* wfeat = (__hip_bfloat16*)ws;
        int*  head = (int*)(ws + HEADE_OFF);
        int4* rec  = (int4*)(ws + REC_OFF);

        hipMemsetAsync(head, 0xFF, (size_t)NNODES * 4, stream);
        hipLaunchKernelGGL(k_link_emb, dim3(2048), dim3(256), 0, stream,
                           src, dst, et, norm, head, rec);
        hipLaunchKernelGGL((rgcn_proj<0>), gridP, dim3(256), 0, stream,
                           feat, weight, w_comp, h_bias, loop_w, wfeat, out);
        hipLaunchKernelGGL(k_agg_emb8, dim3(NNODES / 32), dim3(256), 0, stream,
                           head, rec, wfeat, out);
    } else if (ws_size >= WS_NEED) {
        __hip_bfloat16* wfeat = (__hip_bfloat16*)ws;
        int* head = (int*)(ws + HEAD_OFF);
        int* next = (int*)(ws + NEXT_OFF);

        hipMemsetAsync(head, 0xFF, (size_t)NNODES * 4, stream);
        hipLaunchKernelGGL(k_link, dim3(2048), dim3(256), 0, stream,
                           dst, head, next);
        hipLaunchKernelGGL((rgcn_proj<0>), gridP, dim3(256), 0, stream,
                           feat, weight, w_comp, h_bias, loop_w, wfeat, out);
        hipLaunchKernelGGL(k_agg, dim3(NNODES / 32), dim3(256), 0, stream,
                           head, next, src, et, norm, wfeat, out);
    } else if (ws_size >= WF_BYTES) {
        __hip_bfloat16* wfeat = (__hip_bfloat16*)ws;
        hipLaunchKernelGGL((rgcn_proj<0>), gridP, dim3(256), 0, stream,
                           feat, weight, w_comp, h_bias, loop_w, wfeat, out);
        hipLaunchKernelGGL(rgcn_edge_a, dim3(2048), dim3(256), 0, stream,
                           src, dst, et, norm, wfeat, out);
    } else if (ws_size >= (size_t)NNODES * 256 * 2) {
        __hip_bfloat16* proj = (__hip_bfloat16*)ws;
        hipLaunchKernelGGL((rgcn_proj<1>), gridP, dim3(256), 0, stream,
                           feat, weight, w_comp, h_bias, loop_w, proj, out);
        hipLaunchKernelGGL(rgcn_edge_b, dim3(2048), dim3(256), 0, stream,
                           src, dst, et, norm, proj, w_comp, out);
    } else {
        hipLaunchKernelGGL((rgcn_proj<2>), gridP, dim3(256), 0, stream,
                           feat, weight, w_comp, h_bias, loop_w,
                           (__hip_bfloat16*)nullptr, out);
        hipLaunchKernelGGL(rgcn_edge_c, dim3(2048), dim3(256), 0, stream,
                           src, dst, et, norm, feat, weight, w_comp, out);
    }
}

// Round 12
// 292.378 us; speedup vs baseline: 1.3101x; 1.3101x over previous
//
#include <hip/hip_runtime.h>
#include <hip/hip_bf16.h>

// RGCN basis-decomposition forward, round 12.
//
// Round-11 post-mortem: first-check passed (0.0625) but post-timing output
// diverged deterministically (4.73) -> persistent-state defect in the packed
// 8B-rec / 576-col-wfeat path that inspection couldn't localize. REVERTED to
// the exact round-9 proven path (289us):
//   k_init (NEW, safe): wcat compute + head=-1 init in one kernel (removes
//          the separate hipMemsetAsync node + one dispatch).
//   k_fused: interleaved proj-MFMA (int4 rec, wfeat[N][512], out=bias+selfloop
//          f32) + link role. Bit-identical to round 9.
//   k_agg_emb: 8-chain batch-then-consume, out += acc. Bit-identical to r9.

constexpr int NNODES = 100000;
constexpr int NEDGES = 1600000;

// ---- workspace layout (bytes) ----
constexpr size_t WF_BYTES  = (size_t)NNODES * 512 * 2;         // 102,400,000
constexpr size_t HEADE_OFF = WF_BYTES;                         // int[N]
constexpr size_t REC_OFF   = HEADE_OFF + (size_t)NNODES * 4;   // int4[E]
constexpr size_t WS_NEED_E = REC_OFF + (size_t)NEDGES * 16;    // 128,400,000
constexpr size_t WCAT_OFF  = WS_NEED_E;                        // bf16[576][64]
constexpr size_t WS_NEED_M = WCAT_OFF + (size_t)576 * 64 * 2;  // 128,473,728
// legacy split path:
constexpr size_t HEAD_OFF  = WF_BYTES;
constexpr size_t NEXT_OFF  = HEAD_OFF + (size_t)NNODES * 4;
constexpr size_t WS_NEED   = NEXT_OFF + (size_t)NEDGES * 4;    // 109,200,000

typedef __attribute__((ext_vector_type(8))) short short8v;  // 8 bf16
typedef __attribute__((ext_vector_type(4))) float f32x4;    // MFMA acc

// ---------------------------------------------------------------------------
// k_init: Wcat_t[c][i] bf16 (c<512: basis-combined W_r; c>=512: loop_w)
//         + head[] = -1 (grid-stride). Replaces k_wcat + hipMemsetAsync.
// ---------------------------------------------------------------------------
__global__ __launch_bounds__(256)
void k_init(const float* __restrict__ weight, const float* __restrict__ w_comp,
            const float* __restrict__ loop_w, __hip_bfloat16* __restrict__ wcat,
            int* __restrict__ head)
{
    const int idx = blockIdx.x * 256 + threadIdx.x;   // grid 144 -> 36864
    if (idx < 576 * 64) {
        const int c = idx >> 6, i = idx & 63;
        float v;
        if (c < 512) {
            const int r = c >> 6, o = c & 63;
            v = w_comp[r * 4 + 0] * weight[        i * 64 + o]
              + w_comp[r * 4 + 1] * weight[ 4096 + i * 64 + o]
              + w_comp[r * 4 + 2] * weight[ 8192 + i * 64 + o]
              + w_comp[r * 4 + 3] * weight[12288 + i * 64 + o];
        } else {
            v = loop_w[i * 64 + (c - 512)];
        }
        wcat[(size_t)c * 64 + i] = __float2bfloat16(v);
    }
    for (int j = idx; j < NNODES; j += 144 * 256)
        head[j] = -1;
}

// ---------------------------------------------------------------------------
// k_fused: EXACT round-9 kernel. Grid 4687:
//   bid%3<2 -> proj tile (pidx = g*2+rrole in 0..3124), bid%3==2 -> link.
// proj: C[32x576] = feat_bf16 @ Wcat via mfma_f32_16x16x32_bf16 (m89 layout:
//   A m=lane&15,k=(lane>>4)*8+j; B n=lane&15; C n=lane&15,m=(lane>>4)*4+q).
//   cols<512 -> wfeat bf16 via Clds transpose; cols>=512 -> out=bias+selfloop.
// link: rec[e] = {next, src*512+et*64, norm_bits, 0} (int4, coalesced store).
// ---------------------------------------------------------------------------
__global__ __launch_bounds__(256)
void k_fused(const float* __restrict__ feat,
             const __hip_bfloat16* __restrict__ wcat,   // [576][64]
             const float* __restrict__ h_bias,
             __hip_bfloat16* __restrict__ wfeat,        // [N][512]
             float* __restrict__ out,                   // [N][64]
             const int* __restrict__ src, const int* __restrict__ dst,
             const int* __restrict__ et, const float* __restrict__ norm,
             int* __restrict__ head, int4* __restrict__ rec)
{
    __shared__ __hip_bfloat16 Alds[32 * 72];    // A tile, +8 pad
    __shared__ __hip_bfloat16 Clds[32 * 520];   // wfeat cols, +8 pad

    const int bid = blockIdx.x;
    const int t = threadIdx.x;
    const int g = bid / 3;
    const int rrole = bid - g * 3;

    if (rrole == 2) {
        // ================= link role (1562 blocks) =================
        const int i = g * 256 + t;
        const int stride = 1562 * 256;
        for (int e = i; e < NEDGES; e += stride) {
            const int d = dst[e];
            const int s = src[e];
            const int rr = et[e];
            const float nm = norm[e];
            const int old = atomicExch(&head[d], e);
            rec[e] = make_int4(old, s * 512 + rr * 64, __float_as_int(nm), 0);
        }
        return;
    }

    // ================= proj role (3125 blocks) =================
    const int pidx = g * 2 + rrole;          // 0..3124
    const int lane = t & 63;
    const int wv = t >> 6;                   // 0..3
    const int nbase = pidx * 32;

    {   // stage feat tile (32x64 f32 -> bf16 LDS), coalesced float4
        const float4* fsrc = (const float4*)(feat + (size_t)nbase * 64);
        #pragma unroll
        for (int kk = 0; kk < 2; ++kk) {
            const int idx = t + kk * 256;          // 0..511 float4s
            const float4 f = fsrc[idx];
            const int row = idx >> 4;
            const int c4  = (idx & 15) * 4;
            __hip_bfloat16* p = &Alds[row * 72 + c4];
            p[0] = __float2bfloat16(f.x);
            p[1] = __float2bfloat16(f.y);
            p[2] = __float2bfloat16(f.z);
            p[3] = __float2bfloat16(f.w);
        }
    }
    __syncthreads();

    const int colbase = wv * 144;
    const int lr = lane & 15;
    const int lg = lane >> 4;

    f32x4 acc[2][9];
    #pragma unroll
    for (int mf = 0; mf < 2; ++mf)
        #pragma unroll
        for (int nf = 0; nf < 9; ++nf)
            acc[mf][nf] = (f32x4){0.f, 0.f, 0.f, 0.f};

    #pragma unroll
    for (int ks = 0; ks < 2; ++ks) {
        short8v a[2];
        #pragma unroll
        for (int mf = 0; mf < 2; ++mf)
            a[mf] = *(const short8v*)&Alds[(mf * 16 + lr) * 72 + ks * 32 + lg * 8];
        short8v b[9];
        #pragma unroll
        for (int nf = 0; nf < 9; ++nf) {
            const int col = colbase + nf * 16 + lr;
            b[nf] = *(const short8v*)&wcat[(size_t)col * 64 + ks * 32 + lg * 8];
        }
        #pragma unroll
        for (int mf = 0; mf < 2; ++mf)
            #pragma unroll
            for (int nf = 0; nf < 9; ++nf)
                acc[mf][nf] = __builtin_amdgcn_mfma_f32_16x16x32_bf16(
                    a[mf], b[nf], acc[mf][nf], 0, 0, 0);
    }

    // ---- epilogue: wfeat cols -> Clds (transpose), out cols -> direct ----
    #pragma unroll
    for (int mf = 0; mf < 2; ++mf) {
        #pragma unroll
        for (int nf = 0; nf < 9; ++nf) {
            const int gc = colbase + nf * 16 + lr;
            const int mrow = mf * 16 + lg * 4;
            if (gc < 512) {
                #pragma unroll
                for (int q = 0; q < 4; ++q)
                    Clds[(mrow + q) * 520 + gc] = __float2bfloat16(acc[mf][nf][q]);
            } else {
                const int o = gc - 512;
                const float bias = h_bias[o];
                #pragma unroll
                for (int q = 0; q < 4; ++q)
                    out[(size_t)(nbase + mrow + q) * 64 + o] = bias + acc[mf][nf][q];
            }
        }
    }
    __syncthreads();

    // coalesced wfeat store: one node row (1KB) per wave per pass
    #pragma unroll
    for (int p = 0; p < 8; ++p) {
        const int node = p * 4 + wv;
        const uint4 v = *(const uint4*)&Clds[node * 520 + lane * 8];
        *(uint4*)((char*)(wfeat + (size_t)(nbase + node) * 512) + lane * 16) = v;
    }
}

// ---------------------------------------------------------------------------
// k_agg_emb: EXACT round-9 kernel. 8 chains/wave, batch-then-consume.
// ---------------------------------------------------------------------------
__global__ __launch_bounds__(256)
void k_agg_emb(const int* __restrict__ head, const int4* __restrict__ rec,
               const __hip_bfloat16* __restrict__ wfeat,
               float* __restrict__ out)
{
    const int lane = threadIdx.x & 63;
    const int wid = (int)((blockIdx.x * blockDim.x + threadIdx.x) >> 6);
    const int n0 = wid * 8;

    int   e[8];
    float acc[8];
    bool alive = false;
    #pragma unroll
    for (int k = 0; k < 8; ++k) {
        e[k] = head[n0 + k];
        acc[k] = 0.0f;
        alive = alive || (e[k] >= 0);
    }

    while (alive) {
        int4 R[8];
        #pragma unroll
        for (int k = 0; k < 8; ++k)
            R[k] = rec[(e[k] >= 0) ? e[k] : 0];
        float w[8];
        #pragma unroll
        for (int k = 0; k < 8; ++k)
            w[k] = __bfloat162float(wfeat[(size_t)R[k].y + lane]);
        alive = false;
        #pragma unroll
        for (int k = 0; k < 8; ++k) {
            if (e[k] >= 0) {
                acc[k] = fmaf(__int_as_float(R[k].z), w[k], acc[k]);
                e[k] = R[k].x;
            }
            alive = alive || (e[k] >= 0);
        }
    }

    #pragma unroll
    for (int k = 0; k < 8; ++k)
        out[(size_t)(n0 + k) * 64 + lane] += acc[k];
}

// ---------------------------------------------------------------------------
// Fallback kernels (proven in earlier rounds; legacy layouts).
// ---------------------------------------------------------------------------
__global__ __launch_bounds__(256)
void k_link_emb(const int* __restrict__ src, const int* __restrict__ dst,
                const int* __restrict__ et, const float* __restrict__ norm,
                int* __restrict__ head, int4* __restrict__ rec)
{
    const int i = blockIdx.x * blockDim.x + threadIdx.x;
    const int stride = gridDim.x * blockDim.x;
    for (int e = i; e < NEDGES; e += stride) {
        const int d = dst[e];
        const int s = src[e];
        const int r = et[e];
        const float nm = norm[e];
        const int old = atomicExch(&head[d], e);
        rec[e] = make_int4(old, s * 512 + r * 64, __float_as_int(nm), 0);
    }
}

template <int PATH>
__global__ __launch_bounds__(256)
void rgcn_proj(const float* __restrict__ feat,
               const float* __restrict__ weight,
               const float* __restrict__ w_comp,
               const float* __restrict__ h_bias,
               const float* __restrict__ loop_w,
               __hip_bfloat16* __restrict__ table,
               float* __restrict__ out)
{
    __shared__ float featl[32 * 64];

    const int t = threadIdx.x;
    const int nbase = blockIdx.x * 32;

    {
        const float4* fsrc = (const float4*)(feat + (size_t)nbase * 64);
        float4* fdst = (float4*)featl;
        fdst[t] = fsrc[t];
        fdst[t + 256] = fsrc[t + 256];
    }

    const int lane = t & 63;
    const int n0 = (t >> 6) * 8;
    const float bias = h_bias[lane];

    __syncthreads();

    constexpr int NM = (PATH == 2) ? 1 : 5;
    float acc[8][NM];
    #pragma unroll
    for (int n = 0; n < 8; ++n)
        #pragma unroll
        for (int m = 0; m < NM; ++m)
            acc[n][m] = 0.0f;

    #pragma unroll 4
    for (int i0 = 0; i0 < 64; i0 += 4) {
        float4 f4[8];
        #pragma unroll
        for (int n = 0; n < 8; ++n)
            f4[n] = *(const float4*)&featl[(n0 + n) * 64 + i0];
        #pragma unroll
        for (int q = 0; q < 4; ++q) {
            const int i = i0 + q;
            float vv[NM];
            if (PATH < 2) {
                #pragma unroll
                for (int b = 0; b < 4; ++b)
                    vv[b] = weight[b * 4096 + i * 64 + lane];
                vv[4] = loop_w[i * 64 + lane];
            } else {
                vv[0] = loop_w[i * 64 + lane];
            }
            #pragma unroll
            for (int n = 0; n < 8; ++n) {
                const float fv = (q == 0) ? f4[n].x : (q == 1) ? f4[n].y
                               : (q == 2) ? f4[n].z : f4[n].w;
                #pragma unroll
                for (int m = 0; m < NM; ++m)
                    acc[n][m] = fmaf(fv, vv[m], acc[n][m]);
            }
        }
    }

    float wc[8][4];
    if (PATH == 0) {
        #pragma unroll
        for (int r = 0; r < 8; ++r)
            #pragma unroll
            for (int b = 0; b < 4; ++b)
                wc[r][b] = w_comp[r * 4 + b];
    }

    #pragma unroll
    for (int n = 0; n < 8; ++n) {
        const size_t gn = (size_t)(nbase + n0 + n);
        out[gn * 64 + lane] = bias + acc[n][NM - 1];
        if (PATH == 0) {
            #pragma unroll
            for (int r = 0; r < 8; ++r) {
                const float w = fmaf(wc[r][0], acc[n][0],
                                fmaf(wc[r][1], acc[n][1],
                                fmaf(wc[r][2], acc[n][2],
                                     wc[r][3] * acc[n][3])));
                table[gn * 512 + (size_t)r * 64 + lane] = __float2bfloat16(w);
            }
        } else if (PATH == 1) {
            #pragma unroll
            for (int b = 0; b < 4; ++b)
                table[gn * 256 + (size_t)b * 64 + lane] = __float2bfloat16(acc[n][b]);
        }
    }
}

__global__ __launch_bounds__(256)
void k_link(const int* __restrict__ dst, int* __restrict__ head,
            int* __restrict__ next)
{
    const int i = blockIdx.x * blockDim.x + threadIdx.x;
    const int stride = gridDim.x * blockDim.x;
    for (int e = i; e < NEDGES; e += stride) {
        const int d = dst[e];
        const int old = atomicExch(&head[d], e);
        next[e] = old;
    }
}

__global__ __launch_bounds__(256)
void k_agg(const int* __restrict__ head, const int* __restrict__ next,
           const int* __restrict__ src, const int* __restrict__ et,
           const float* __restrict__ norm,
           const __hip_bfloat16* __restrict__ wfeat,
           float* __restrict__ out)
{
    const int lane = threadIdx.x & 63;
    const int wid = (int)((blockIdx.x * blockDim.x + threadIdx.x) >> 6);
    const int n0 = wid * 8;

    int   e[8];
    float acc[8];
    #pragma unroll
    for (int k = 0; k < 8; ++k) {
        e[k] = head[n0 + k];
        acc[k] = 0.0f;
    }

    while (true) {
        bool progress = false;
        #pragma unroll
        for (int k = 0; k < 8; ++k) {
            const int ek = e[k];
            if (ek >= 0) {
                progress = true;
                const int   s = src[ek];
                const int   r = et[ek];
                const float m = norm[ek];
                const float w = __bfloat162float(
                    wfeat[(size_t)s * 512 + (size_t)r * 64 + lane]);
                acc[k] = fmaf(m, w, acc[k]);
                e[k] = next[ek];
            }
        }
        if (!progress) break;
    }

    #pragma unroll
    for (int k = 0; k < 8; ++k)
        out[(size_t)(n0 + k) * 64 + lane] += acc[k];
}

__global__ __launch_bounds__(256)
void rgcn_edge_a(const int* __restrict__ src, const int* __restrict__ dst,
                 const int* __restrict__ et, const float* __restrict__ norm,
                 const __hip_bfloat16* __restrict__ wfeat,
                 float* __restrict__ out)
{
    const int lane = threadIdx.x & 63;
    const int wid  = (int)((blockIdx.x * blockDim.x + threadIdx.x) >> 6);
    const int nw   = (int)((gridDim.x * blockDim.x) >> 6);
    for (int e = wid; e < NEDGES; e += nw) {
        const int   s  = src[e];
        const int   d  = dst[e];
        const int   r  = et[e];
        const float nm = norm[e];
        const float w  = __bfloat162float(wfeat[(size_t)s * 512 + (size_t)r * 64 + lane]);
        atomicAdd(out + (size_t)d * 64 + lane, w * nm);
    }
}

__global__ __launch_bounds__(256)
void rgcn_edge_b(const int* __restrict__ src, const int* __restrict__ dst,
                 const int* __restrict__ et, const float* __restrict__ norm,
                 const __hip_bfloat16* __restrict__ proj,
                 const float* __restrict__ w_comp,
                 float* __restrict__ out)
{
    const int lane = threadIdx.x & 63;
    const int wid  = (int)((blockIdx.x * blockDim.x + threadIdx.x) >> 6);
    const int nw   = (int)((gridDim.x * blockDim.x) >> 6);
    for (int e = wid; e < NEDGES; e += nw) {
        const int   s  = src[e];
        const int   d  = dst[e];
        const int   r  = et[e];
        const float nm = norm[e];
        const __hip_bfloat16* p = proj + (size_t)s * 256;
        float m = w_comp[r * 4 + 0] * __bfloat162float(p[lane]);
        m = fmaf(w_comp[r * 4 + 1], __bfloat162float(p[ 64 + lane]), m);
        m = fmaf(w_comp[r * 4 + 2], __bfloat162float(p[128 + lane]), m);
        m = fmaf(w_comp[r * 4 + 3], __bfloat162float(p[192 + lane]), m);
        atomicAdd(out + (size_t)d * 64 + lane, m * nm);
    }
}

__global__ __launch_bounds__(256)
void rgcn_edge_c(const int* __restrict__ src, const int* __restrict__ dst,
                 const int* __restrict__ et, const float* __restrict__ norm,
                 const float* __restrict__ feat,
                 const float* __restrict__ weight,
                 const float* __restrict__ w_comp,
                 float* __restrict__ out)
{
    __shared__ __hip_bfloat16 Vl[4 * 64 * 64];
    const int t = threadIdx.x;
    #pragma unroll
    for (int k = 0; k < 64; ++k)
        Vl[t + k * 256] = __float2bfloat16(weight[t + k * 256]);
    __syncthreads();

    const int lane = t & 63;
    const int wid  = (int)((blockIdx.x * blockDim.x + t) >> 6);
    const int nw   = (int)((gridDim.x * blockDim.x) >> 6);
    for (int e = wid; e < NEDGES; e += nw) {
        const int   s  = src[e];
        const int   d  = dst[e];
        const int   r  = et[e];
        const float nm = norm[e];
        const float wc0 = w_comp[r * 4 + 0], wc1 = w_comp[r * 4 + 1];
        const float wc2 = w_comp[r * 4 + 2], wc3 = w_comp[r * 4 + 3];
        const float f = feat[(size_t)s * 64 + lane];
        float acc = 0.0f;
        #pragma unroll 8
        for (int i = 0; i < 64; ++i) {
            const float fi = __shfl(f, i);
            float w =        wc0 * __bfloat162float(Vl[          i * 64 + lane]);
            w = fmaf(wc1, __bfloat162float(Vl[ 4096 + i * 64 + lane]), w);
            w = fmaf(wc2, __bfloat162float(Vl[ 8192 + i * 64 + lane]), w);
            w = fmaf(wc3, __bfloat162float(Vl[12288 + i * 64 + lane]), w);
            acc = fmaf(fi, w, acc);
        }
        atomicAdd(out + (size_t)d * 64 + lane, acc * nm);
    }
}

// ---------------------------------------------------------------------------
extern "C" void kernel_launch(void* const* d_in, const int* in_sizes, int n_in,
                              void* d_out, int out_size, void* d_ws, size_t ws_size,
                              hipStream_t stream) {
    const float* feat   = (const float*)d_in[0];
    const int*   src    = (const int*)  d_in[1];
    const int*   dst    = (const int*)  d_in[2];
    const int*   et     = (const int*)  d_in[3];
    const float* norm   = (const float*)d_in[4];
    const float* weight = (const float*)d_in[5];
    const float* w_comp = (const float*)d_in[6];
    const float* h_bias = (const float*)d_in[7];
    const float* loop_w = (const float*)d_in[8];
    float* out = (float*)d_out;
    char* ws = (char*)d_ws;

    const dim3 gridP(NNODES / 32);  // 3125

    if (ws_size >= WS_NEED_M) {
        // ---- proven round-9 path (+ memset folded into k_init) ----
        __hip_bfloat16* wfeat = (__hip_bfloat16*)ws;            // [N][512]
        int*  head = (int*)(ws + HEADE_OFF);
        int4* rec  = (int4*)(ws + REC_OFF);
        __hip_bfloat16* wcat = (__hip_bfloat16*)(ws + WCAT_OFF);

        hipLaunchKernelGGL(k_init, dim3(144), dim3(256), 0, stream,
                           weight, w_comp, loop_w, wcat, head);
        hipLaunchKernelGGL(k_fused, dim3(4687), dim3(256), 0, stream,
                           feat, wcat, h_bias, wfeat, out,
                           src, dst, et, norm, head, rec);
        hipLaunchKernelGGL(k_agg_emb, dim3(NNODES / 32), dim3(256), 0, stream,
                           head, rec, wfeat, out);
    } else if (ws_size >= WS_NEED_E) {
        // ---- round-7 proven path ----
        __hip_bfloat16* wfeat = (__hip_bfloat16*)ws;
        int*  head = (int*)(ws + HEADE_OFF);
        int4* rec  = (int4*)(ws + REC_OFF);

        hipMemsetAsync(head, 0xFF, (size_t)NNODES * 4, stream);
        hipLaunchKernelGGL(k_link_emb, dim3(2048), dim3(256), 0, stream,
                           src, dst, et, norm, head, rec);
        hipLaunchKernelGGL((rgcn_proj<0>), gridP, dim3(256), 0, stream,
                           feat, weight, w_comp, h_bias, loop_w, wfeat, out);
        hipLaunchKernelGGL(k_agg_emb, dim3(NNODES / 32), dim3(256), 0, stream,
                           head, rec, wfeat, out);
    } else if (ws_size >= WS_NEED) {
        __hip_bfloat16* wfeat = (__hip_bfloat16*)ws;
        int* head = (int*)(ws + HEAD_OFF);
        int* next = (int*)(ws + NEXT_OFF);

        hipMemsetAsync(head, 0xFF, (size_t)NNODES * 4, stream);
        hipLaunchKernelGGL(k_link, dim3(2048), dim3(256), 0, stream,
                           dst, head, next);
        hipLaunchKernelGGL((rgcn_proj<0>), gridP, dim3(256), 0, stream,
                           feat, weight, w_comp, h_bias, loop_w, wfeat, out);
        hipLaunchKernelGGL(k_agg, dim3(NNODES / 32), dim3(256), 0, stream,
                           head, next, src, et, norm, wfeat, out);
    } else if (ws_size >= WF_BYTES) {
        __hip_bfloat16* wfeat = (__hip_bfloat16*)ws;
        hipLaunchKernelGGL((rgcn_proj<0>), gridP, dim3(256), 0, stream,
                           feat, weight, w_comp, h_bias, loop_w, wfeat, out);
        hipLaunchKernelGGL(rgcn_edge_a, dim3(2048), dim3(256), 0, stream,
                           src, dst, et, norm, wfeat, out);
    } else if (ws_size >= (size_t)NNODES * 256 * 2) {
        __hip_bfloat16* proj = (__hip_bfloat16*)ws;
        hipLaunchKernelGGL((rgcn_proj<1>), gridP, dim3(256), 0, stream,
                           feat, weight, w_comp, h_bias, loop_w, proj, out);
        hipLaunchKernelGGL(rgcn_edge_b, dim3(2048), dim3(256), 0, stream,
                           src, dst, et, norm, proj, w_comp, out);
    } else {
        hipLaunchKernelGGL((rgcn_proj<2>), gridP, dim3(256), 0, stream,
                           feat, weight, w_comp, h_bias, loop_w,
                           (__hip_bfloat16*)nullptr, out);
        hipLaunchKernelGGL(rgcn_edge_c, dim3(2048), dim3(256), 0, stream,
                           src, dst, et, norm, feat, weight, w_comp, out);
    }
}